// Round 6
// baseline (943.561 us; speedup 1.0000x reference)
//
#include <hip/hip_runtime.h>

#define CIN   256
#define COUT  512
#define HW    1024     // H*W = 32*32
#define ITERS 20

typedef __attribute__((ext_vector_type(8)))  short bf16x8;
typedef __attribute__((ext_vector_type(4)))  float f32x4;
typedef __attribute__((ext_vector_type(16))) float f32x16;
typedef __attribute__((ext_vector_type(2)))  unsigned u32x2;

__device__ __forceinline__ unsigned short f2b(float x) {
  unsigned b = __builtin_bit_cast(unsigned, x);
  unsigned r = (b + 0x7FFFu + ((b >> 16) & 1u)) >> 16;   // RNE
  return (unsigned short)r;
}
// packed f32x2 -> bf16x2 (RNE), lo = a, hi = b
__device__ __forceinline__ unsigned cvt_pk_bf16(float a, float b) {
  unsigned r;
  asm("v_cvt_pk_bf16_f32 %0, %1, %2" : "=v"(r) : "v"(a), "v"(b));
  return r;
}

// 32x32x16 MFMA fragment conventions (gfx950):
//  A-frag: lane l holds row m = l&31,  k = (l>>5)*8 + i  (i=0..7)
//  B-frag: lane l holds col n = l&31,  k = (l>>5)*8 + i
//  C/D   : col = lane&31, row = (r&3) + 8*(r>>2) + 4*(lane>>5), r in [0,16)
//
// Both GEMMs computed TRANSPOSED (A = weights, B = h/y, cols = pixels).
//
// w1: GEMM1 A-frags [ct:8][kt:32][lane:64][i:8];  c = ct*32+(l&31), j = kt*16+(l>>5)*8+i
// w2: GEMM2 A-frags [jt:16][kt:16][lane:64][i:8]; j = jt*32+(l&31), c = kt*16+(l>>5)*8+i
__global__ __launch_bounds__(256) void prep_weights(const float* __restrict__ w,
                                                    unsigned short* __restrict__ w1,
                                                    unsigned short* __restrict__ w2) {
  int f = blockIdx.x * 256 + threadIdx.x;   // [0, 131072)
  {
    int i = f & 7, l = (f >> 3) & 63, kt = (f >> 9) & 31, ct = f >> 14;
    int c = ct * 32 + (l & 31);
    int j = kt * 16 + ((l >> 5) << 3) + i;
    w1[f] = f2b(w[j * CIN + c]);
  }
  {
    int i = f & 7, l = (f >> 3) & 63, kt = (f >> 9) & 15, jt = f >> 13;
    int j = jt * 32 + (l & 31);
    int c = kt * 16 + ((l >> 5) << 3) + i;
    w2[f] = f2b(w[j * CIN + c]);
  }
}

// R6: "R3 done right" — 32 px / 256 threads / 4 waves per block, all 20 iters on-chip.
// R5 analysis: true MFMA/VALU busy ~6%/5%; ~90% stall; latency-bound at 2 waves/SIMD
// with barrier-locked phases. This structure: LDS 48.7KB -> 3 blocks/CU = 3 waves/SIMD,
// AND 3 independent blocks interleave phases (one block's MFMA hides another's
// barrier/restage). __launch_bounds__(256,3) caps unified regs at 170; demand ~155
// (hreg 64 + x_pk 16 + acc 32 AGPR + transients) -> no R1-style coerced spill.
// R3's actual failure was no-bounds -> 192+ regs -> 1 wave/SIMD; fixed here.
// Cost: weight L2 traffic 5.4 -> 10.7 GB (aggregate-L2 floor ~310us) — next wall.
__global__ __launch_bounds__(256, 3) void nnmf_kernel(const float* __restrict__ xin,
                                                      const unsigned short* __restrict__ w1,
                                                      const unsigned short* __restrict__ w2,
                                                      float* __restrict__ out) {
  __shared__ __align__(16) unsigned short hA[32 * 512]; // 32KB  B-frags GEMM1 (k=j)
  __shared__ __align__(16) unsigned short yF[16 * 512]; // 16KB  B-frags GEMM2 (k=c)
  __shared__ float red[32 * 4];                         // 512B  per-px partials

  const int tid  = threadIdx.x;
  const int wv   = tid >> 6;      // 0..3
  const int lane = tid & 63;
  const int px   = lane & 31;     // pixel (C col)
  const int hi   = lane >> 5;

  const int wg     = blockIdx.x;       // 1024 blocks
  const int bb     = wg >> 5;          // image
  const int hwbase = (wg & 31) * 32;   // 32 consecutive pixels
  const float* xbase = xin + (size_t)bb * (CIN * HW) + hwbase + px;

  // ---- x in registers, GEMM1-C row layout, bf16 packed pairs (16 VGPRs) ----
  // c(ct,r) = (wv*2+ct)*32 + (r&3) + 8*(r>>2) + 4*hi ; pair q packs r=2q,2q+1
  unsigned x_pk[2][8];
#pragma unroll
  for (int ct = 0; ct < 2; ++ct)
#pragma unroll
    for (int q = 0; q < 8; ++q) {
      int c = (wv * 2 + ct) * 32 + 2 * (q & 1) + 8 * (q >> 1) + 4 * hi;
      x_pk[ct][q] = cvt_pk_bf16(xbase[c * HW], xbase[(c + 1) * HW]);
    }

  // ---- init hA = bf16(1/512) (exact): 8192 u32 words / 256 threads ----
  {
    unsigned* h32 = (unsigned*)hA;
#pragma unroll
    for (int g = 0; g < 32; ++g) h32[tid + (g << 8)] = 0x3B003B00u;  // two bf16(2^-9)
  }

  // persistent fp32 h: j = (wv*4+n)*32 + (r&3)+8*(r>>2)+4*hi, col = hwbase+px
  f32x16 hreg[4];
#pragma unroll
  for (int n = 0; n < 4; ++n)
#pragma unroll
    for (int r = 0; r < 16; ++r) hreg[n][r] = 1.0f / 512.0f;

  const unsigned short* w1w = w1 + (size_t)(wv * 2) * (32 * 512) + lane * 8; // ct = 2wv+{0,1}
  const unsigned short* w2w = w2 + (size_t)(wv * 4) * (16 * 512) + lane * 8; // jt = 4wv+{0..3}
  const unsigned short* hAr = hA + lane * 8;
  const unsigned short* yFr = yF + lane * 8;

  __syncthreads();

  for (int it = 0; it < ITERS; ++it) {
    // ===== GEMM1 (swapped): rec^T[c][px] = sum_j W[j][c] h[px][j] =====
    // 2 parallel ct chains; per kt: 2 a-loads (L2) + 1 b-read (LDS) -> 2 MFMAs.
    f32x16 acc1[2];
#pragma unroll
    for (int ct = 0; ct < 2; ++ct)
#pragma unroll
      for (int r = 0; r < 16; ++r) acc1[ct][r] = 0.0f;

#pragma unroll 2
    for (int kt = 0; kt < 32; ++kt) {
      bf16x8 b  = *(const bf16x8*)(hAr + kt * 512);
      bf16x8 a0 = *(const bf16x8*)(w1w + kt * 512);
      bf16x8 a1 = *(const bf16x8*)(w1w + (32 + kt) * 512);   // ct+1 slice
      acc1[0] = __builtin_amdgcn_mfma_f32_32x32x16_bf16(a0, b, acc1[0], 0, 0, 0);
      acc1[1] = __builtin_amdgcn_mfma_f32_32x32x16_bf16(a1, b, acc1[1], 0, 0, 0);
    }

    // y = x / (rec + 1e-20) -> yF (GEMM2 B-frag layout), single b64 stores
    // c = (wv*2+ct)*32 + 8*rb + 4*hi + t ; kt2=(wv*2+ct)*2+(rb>>1); slot=((rb&1)<<5)+px
#pragma unroll
    for (int ct = 0; ct < 2; ++ct)
#pragma unroll
      for (int rb = 0; rb < 4; ++rb) {
        unsigned xa = x_pk[ct][2 * rb], xb = x_pk[ct][2 * rb + 1];
        float x0 = __builtin_bit_cast(float, xa << 16);
        float x1 = __builtin_bit_cast(float, xa & 0xffff0000u);
        float x2 = __builtin_bit_cast(float, xb << 16);
        float x3 = __builtin_bit_cast(float, xb & 0xffff0000u);
        float y0 = x0 * __builtin_amdgcn_rcpf(acc1[ct][4 * rb + 0] + 1e-20f);
        float y1 = x1 * __builtin_amdgcn_rcpf(acc1[ct][4 * rb + 1] + 1e-20f);
        float y2 = x2 * __builtin_amdgcn_rcpf(acc1[ct][4 * rb + 2] + 1e-20f);
        float y3 = x3 * __builtin_amdgcn_rcpf(acc1[ct][4 * rb + 3] + 1e-20f);
        int kt2 = (wv * 2 + ct) * 2 + (rb >> 1);
        u32x2 pk = { cvt_pk_bf16(y0, y1), cvt_pk_bf16(y2, y3) };
        *(u32x2*)(yF + ((kt2 * 64 + ((rb & 1) << 5) + px) << 3) + (hi << 2)) = pk;
      }
    __syncthreads();   // (a) yF complete

    // ===== GEMM2 (swapped): t^T[j][px] = sum_c W[j][c] y[px][c] =====
    // 4 jt in 2 passes of 2 parallel chains; acc2 = 32 live (AGPR).
    float psum = 0.0f;
#pragma unroll
    for (int p = 0; p < 2; ++p) {
      f32x16 acc2[2];
#pragma unroll
      for (int n = 0; n < 2; ++n)
#pragma unroll
        for (int r = 0; r < 16; ++r) acc2[n][r] = 0.0f;
#pragma unroll 2
      for (int kt = 0; kt < 16; ++kt) {
        bf16x8 b  = *(const bf16x8*)(yFr + kt * 512);
        bf16x8 a0 = *(const bf16x8*)(w2w + ((p * 2 + 0) * 16 + kt) * 512);
        bf16x8 a1 = *(const bf16x8*)(w2w + ((p * 2 + 1) * 16 + kt) * 512);
        acc2[0] = __builtin_amdgcn_mfma_f32_32x32x16_bf16(a0, b, acc2[0], 0, 0, 0);
        acc2[1] = __builtin_amdgcn_mfma_f32_32x32x16_bf16(a1, b, acc2[1], 0, 0, 0);
      }
#pragma unroll
      for (int n = 0; n < 2; ++n)
#pragma unroll
        for (int r = 0; r < 16; ++r) {
          int jn = p * 2 + n;
          float hn = hreg[jn][r] * acc2[n][r];
          hreg[jn][r] = hn;
          psum += hn;
        }
    }

    // ===== per-px sum over all 512 j, normalize =====
    psum += __shfl_xor(psum, 32, 64);   // fold complementary row-half (same px)
    if (lane < 32) red[lane * 4 + wv] = psum;
    __syncthreads();   // (b) red visible

    f32x4 pr = *(const f32x4*)(red + px * 4);
    float inv = __builtin_amdgcn_rcpf(pr[0] + pr[1] + pr[2] + pr[3] + 1e-19f);

    if (it < ITERS - 1) {
      // normalize + restage h into hA (GEMM1 B-frag layout), single b64 stores
      // j = (wv*4+n)*32 + 8*rb + 4*hi + t ; kt = (wv*4+n)*2+(rb>>1)
#pragma unroll
      for (int n = 0; n < 4; ++n)
#pragma unroll
        for (int rb = 0; rb < 4; ++rb) {
          float h0 = hreg[n][4 * rb + 0] * inv;
          float h1 = hreg[n][4 * rb + 1] * inv;
          float h2 = hreg[n][4 * rb + 2] * inv;
          float h3 = hreg[n][4 * rb + 3] * inv;
          hreg[n][4 * rb + 0] = h0; hreg[n][4 * rb + 1] = h1;
          hreg[n][4 * rb + 2] = h2; hreg[n][4 * rb + 3] = h3;
          int kt = (wv * 4 + n) * 2 + (rb >> 1);
          u32x2 pk = { cvt_pk_bf16(h0, h1), cvt_pk_bf16(h2, h3) };
          *(u32x2*)(hA + ((kt * 64 + ((rb & 1) << 5) + px) << 3) + (hi << 2)) = pk;
        }
    } else {
      // final store fp32: out[b][j][hw]; lanes 0..31 = consecutive px -> coalesced
      float* obase = out + (size_t)bb * (COUT * HW) + hwbase + px;
#pragma unroll
      for (int n = 0; n < 4; ++n)
#pragma unroll
        for (int r = 0; r < 16; ++r) {
          int j = (wv * 4 + n) * 32 + (r & 3) + 8 * (r >> 2) + 4 * hi;
          obase[j * HW] = hreg[n][r] * inv;
        }
    }
    __syncthreads();   // (c) hA ready / yF & red reusable
  }
}

extern "C" void kernel_launch(void* const* d_in, const int* in_sizes, int n_in,
                              void* d_out, int out_size, void* d_ws, size_t ws_size,
                              hipStream_t stream) {
  const float* x = (const float*)d_in[0];   // [32,256,32,32]
  const float* w = (const float*)d_in[1];   // [512,256]
  unsigned short* w1 = (unsigned short*)d_ws;          // 256 KB
  unsigned short* w2 = w1 + COUT * CIN;                // 256 KB
  float* out = (float*)d_out;

  prep_weights<<<dim3(512), dim3(256), 0, stream>>>(w, w1, w2);
  nnmf_kernel<<<dim3(32768 / 32), dim3(256), 0, stream>>>(x, w1, w2, out);
}

// Round 7
// 490.129 us; speedup vs baseline: 1.9251x; 1.9251x over previous
//
#include <hip/hip_runtime.h>

#define CIN   256
#define COUT  512
#define HW    1024     // H*W = 32*32
#define ITERS 20

typedef __attribute__((ext_vector_type(8)))  short bf16x8;
typedef __attribute__((ext_vector_type(4)))  float f32x4;
typedef __attribute__((ext_vector_type(16))) float f32x16;
typedef __attribute__((ext_vector_type(2)))  unsigned u32x2;

__device__ __forceinline__ unsigned short f2b(float x) {
  unsigned b = __builtin_bit_cast(unsigned, x);
  unsigned r = (b + 0x7FFFu + ((b >> 16) & 1u)) >> 16;   // RNE
  return (unsigned short)r;
}
// packed f32x2 -> bf16x2 (RNE), lo = a, hi = b
__device__ __forceinline__ unsigned cvt_pk_bf16(float a, float b) {
  unsigned r;
  asm("v_cvt_pk_bf16_f32 %0, %1, %2" : "=v"(r) : "v"(a), "v"(b));
  return r;
}

// 32x32x16 MFMA fragment conventions (gfx950):
//  A-frag: lane l holds row m = l&31,  k = (l>>5)*8 + i  (i=0..7)
//  B-frag: lane l holds col n = l&31,  k = (l>>5)*8 + i
//  C/D   : col = lane&31, row = (r&3) + 8*(r>>2) + 4*(lane>>5), r in [0,16)
//
// Both GEMMs computed TRANSPOSED (A = weights, B = h/y, cols = pixels).
//
// w1: GEMM1 A-frags [ct:8][kt:32][lane:64][i:8];  c = ct*32+(l&31), j = kt*16+(l>>5)*8+i
// w2: GEMM2 A-frags [jt:16][kt:16][lane:64][i:8]; j = jt*32+(l&31), c = kt*16+(l>>5)*8+i
__global__ __launch_bounds__(256) void prep_weights(const float* __restrict__ w,
                                                    unsigned short* __restrict__ w1,
                                                    unsigned short* __restrict__ w2) {
  int f = blockIdx.x * 256 + threadIdx.x;   // [0, 131072)
  {
    int i = f & 7, l = (f >> 3) & 63, kt = (f >> 9) & 31, ct = f >> 14;
    int c = ct * 32 + (l & 31);
    int j = kt * 16 + ((l >> 5) << 3) + i;
    w1[f] = f2b(w[j * CIN + c]);
  }
  {
    int i = f & 7, l = (f >> 3) & 63, kt = (f >> 9) & 15, jt = f >> 13;
    int j = jt * 32 + (l & 31);
    int c = kt * 16 + ((l >> 5) << 3) + i;
    w2[f] = f2b(w[j * CIN + c]);
  }
}

// R7: 64 px / 1024 threads / 16 waves per block, 4 waves/SIMD, all 20 iters on-chip.
// R6 lesson (final): fp32 per-thread state must fit the ARCH half of the unified file;
// 64 hreg + 16 x_pk can never run at >2 waves/SIMD. So halve per-wave state instead:
//   GEMM1: wave owns ONE (ct = wv>>1, pt = wv&1) chain  (16 chains = 8ct x 2pt)
//   GEMM2: wave owns ONE jt = wv, both pt (acc2[2] = 32 AGPR, w2 frag reused)
//   -> hreg 32, x in LDS (R5-proven), peak unified ~100 < 128 budget @ (1024,4).
// 4 waves/SIMD doubles latency overlap inside every barrier-locked phase vs R4/R5.
// LDS 133KB (hA 64K + yF 32K + xS 32K + red 5K) -> 1 block/CU.
__global__ __launch_bounds__(1024, 4) void nnmf_kernel(const float* __restrict__ xin,
                                                       const unsigned short* __restrict__ w1,
                                                       const unsigned short* __restrict__ w2,
                                                       float* __restrict__ out) {
  __shared__ __align__(16) unsigned short hA[2 * 32 * 512]; // 64KB  B-frags GEMM1 (k=j), per px-tile
  __shared__ __align__(16) unsigned short yF[2 * 16 * 512]; // 32KB  B-frags GEMM2 (k=c), per px-tile
  __shared__ __align__(16) unsigned xS[2 * 8 * 4 * 2 * 32 * 2]; // 32KB bf16 x, [pt][ct][rb][hi][px][2]
  __shared__ float red[2 * 32 * 20];                        // 5KB per-(pt,px) partials, stride 20

  const int tid  = threadIdx.x;
  const int wv   = tid >> 6;      // 0..15
  const int lane = tid & 63;
  const int px   = lane & 31;     // pixel within tile (C col)
  const int hi   = lane >> 5;

  const int ct = wv >> 1;         // GEMM1 / y-phase: channel slice
  const int pA = wv & 1;          // GEMM1 / y-phase: pixel tile
  const int jt = wv;              // GEMM2 / restage / store: output-channel slice

  const int wg     = blockIdx.x;       // 512 blocks
  const int bb     = wg >> 4;          // image
  const int hwbase = (wg & 15) * 64;   // 64 consecutive pixels
  const float* xbase = xin + (size_t)bb * (CIN * HW) + hwbase + px;

  // ---- stage x into LDS (only this wave's (pA,ct) slice), y-phase layout ----
  // entry (pt,ct,rb,hi,px) holds c = ct*32 + 8*rb + 4*hi + {0,1,2,3}
#pragma unroll
  for (int rb = 0; rb < 4; ++rb) {
    int c0 = ct * 32 + 8 * rb + 4 * hi;
    const float* xp = xbase + pA * 32;
    u32x2 pk = { cvt_pk_bf16(xp[c0 * HW],       xp[(c0 + 1) * HW]),
                 cvt_pk_bf16(xp[(c0 + 2) * HW], xp[(c0 + 3) * HW]) };
    *(u32x2*)(xS + (((((pA * 8 + ct) * 4 + rb) * 2 + hi) * 32 + px) << 1)) = pk;
  }

  // ---- init hA = bf16(1/512) (exact): 16384 u32 words / 1024 threads ----
  {
    unsigned* h32 = (unsigned*)hA;
#pragma unroll
    for (int g = 0; g < 16; ++g) h32[tid + (g << 10)] = 0x3B003B00u;  // two bf16(2^-9)
  }

  // persistent fp32 h: j = wv*32 + (r&3)+8*(r>>2)+4*hi, col = hwbase + pt*32 + px
  f32x16 hreg[2];   // [pt]
#pragma unroll
  for (int pt = 0; pt < 2; ++pt)
#pragma unroll
    for (int r = 0; r < 16; ++r) hreg[pt][r] = 1.0f / 512.0f;

  const unsigned short* w1w = w1 + (size_t)ct * (32 * 512) + lane * 8;
  const unsigned short* w2w = w2 + (size_t)jt * (16 * 512) + lane * 8;
  const unsigned short* hAp = hA + pA * (32 * 512) + lane * 8;
  const unsigned short* yFr = yF + lane * 8;

  __syncthreads();

  for (int it = 0; it < ITERS; ++it) {
    // ===== GEMM1 (swapped): rec^T[c][px] = sum_j W[j][c] h[px][j] =====
    // One chain per wave: 32 MFMA, acc1 = 16 AGPR.
    f32x16 acc1;
#pragma unroll
    for (int r = 0; r < 16; ++r) acc1[r] = 0.0f;

#pragma unroll 4
    for (int kt = 0; kt < 32; ++kt) {
      bf16x8 a = *(const bf16x8*)(w1w + kt * 512);
      bf16x8 b = *(const bf16x8*)(hAp + kt * 512);
      acc1 = __builtin_amdgcn_mfma_f32_32x32x16_bf16(a, b, acc1, 0, 0, 0);
    }

    // y = x / (rec + 1e-20) -> yF (GEMM2 B-frag layout), single b64 stores
    // c = ct*32 + 8*rb + 4*hi + t ; kt2 = ct*2+(rb>>1); slot=((rb&1)<<5)+px; i=4*hi+t
#pragma unroll
    for (int rb = 0; rb < 4; ++rb) {
      u32x2 xp = *(const u32x2*)(xS + (((((pA * 8 + ct) * 4 + rb) * 2 + hi) * 32 + px) << 1));
      float x0 = __builtin_bit_cast(float, xp.x << 16);
      float x1 = __builtin_bit_cast(float, xp.x & 0xffff0000u);
      float x2 = __builtin_bit_cast(float, xp.y << 16);
      float x3 = __builtin_bit_cast(float, xp.y & 0xffff0000u);
      float y0 = x0 * __builtin_amdgcn_rcpf(acc1[4 * rb + 0] + 1e-20f);
      float y1 = x1 * __builtin_amdgcn_rcpf(acc1[4 * rb + 1] + 1e-20f);
      float y2 = x2 * __builtin_amdgcn_rcpf(acc1[4 * rb + 2] + 1e-20f);
      float y3 = x3 * __builtin_amdgcn_rcpf(acc1[4 * rb + 3] + 1e-20f);
      int kt2 = ct * 2 + (rb >> 1);
      u32x2 pk = { cvt_pk_bf16(y0, y1), cvt_pk_bf16(y2, y3) };
      *(u32x2*)(yF + (((pA * 16 + kt2) * 64 + ((rb & 1) << 5) + px) << 3) + (hi << 2)) = pk;
    }
    __syncthreads();   // (a) yF complete

    // ===== GEMM2 (swapped): t^T[j][px] = sum_c W[j][c] y[px][c] =====
    // One jt per wave, both pt; w2 frag loaded once -> 2 MFMAs. acc2 = 32 AGPR.
    f32x16 acc2[2];
#pragma unroll
    for (int pt = 0; pt < 2; ++pt)
#pragma unroll
      for (int r = 0; r < 16; ++r) acc2[pt][r] = 0.0f;

#pragma unroll 2
    for (int kt = 0; kt < 16; ++kt) {
      bf16x8 a  = *(const bf16x8*)(w2w + kt * 512);
      bf16x8 b0 = *(const bf16x8*)(yFr + kt * 512);          // px-tile 0
      bf16x8 b1 = *(const bf16x8*)(yFr + (16 + kt) * 512);   // px-tile 1
      acc2[0] = __builtin_amdgcn_mfma_f32_32x32x16_bf16(a, b0, acc2[0], 0, 0, 0);
      acc2[1] = __builtin_amdgcn_mfma_f32_32x32x16_bf16(a, b1, acc2[1], 0, 0, 0);
    }

    // ===== h *= t ; per-(pt,px) partial sums =====
    float psum0 = 0.0f, psum1 = 0.0f;
#pragma unroll
    for (int r = 0; r < 16; ++r) {
      float hn0 = hreg[0][r] * acc2[0][r];
      float hn1 = hreg[1][r] * acc2[1][r];
      hreg[0][r] = hn0;
      hreg[1][r] = hn1;
      psum0 += hn0;
      psum1 += hn1;
    }
    psum0 += __shfl_xor(psum0, 32, 64);   // fold complementary row-half (same px)
    psum1 += __shfl_xor(psum1, 32, 64);
    if (lane < 32) {
      red[(0 * 32 + px) * 20 + wv] = psum0;
      red[(1 * 32 + px) * 20 + wv] = psum1;
    }
    __syncthreads();   // (b) red visible

    // sum 16 wave-partials per (pt,px): 4x f32x4 (stride 20 -> 16B aligned)
    float inv[2];
#pragma unroll
    for (int pt = 0; pt < 2; ++pt) {
      const float* rp = red + (pt * 32 + px) * 20;
      f32x4 s0 = *(const f32x4*)(rp + 0);
      f32x4 s1 = *(const f32x4*)(rp + 4);
      f32x4 s2 = *(const f32x4*)(rp + 8);
      f32x4 s3 = *(const f32x4*)(rp + 12);
      float s = (s0[0]+s0[1]+s0[2]+s0[3]) + (s1[0]+s1[1]+s1[2]+s1[3])
              + (s2[0]+s2[1]+s2[2]+s2[3]) + (s3[0]+s3[1]+s3[2]+s3[3]);
      inv[pt] = __builtin_amdgcn_rcpf(s + 1e-19f);
    }

    if (it < ITERS - 1) {
      // normalize + restage h into hA (GEMM1 B-frag layout), single b64 stores
      // j = wv*32 + 8*rb + 4*hi + t ; kt = wv*2+(rb>>1); slot=((rb&1)<<5)+px; i=4*hi+t
#pragma unroll
      for (int pt = 0; pt < 2; ++pt)
#pragma unroll
        for (int rb = 0; rb < 4; ++rb) {
          float h0 = hreg[pt][4 * rb + 0] * inv[pt];
          float h1 = hreg[pt][4 * rb + 1] * inv[pt];
          float h2 = hreg[pt][4 * rb + 2] * inv[pt];
          float h3 = hreg[pt][4 * rb + 3] * inv[pt];
          hreg[pt][4 * rb + 0] = h0; hreg[pt][4 * rb + 1] = h1;
          hreg[pt][4 * rb + 2] = h2; hreg[pt][4 * rb + 3] = h3;
          int kt = wv * 2 + (rb >> 1);
          u32x2 pk = { cvt_pk_bf16(h0, h1), cvt_pk_bf16(h2, h3) };
          *(u32x2*)(hA + (((pt * 32 + kt) * 64 + ((rb & 1) << 5) + px) << 3) + (hi << 2)) = pk;
        }
    } else {
      // final store fp32: out[b][j][hw]; lanes = consecutive px -> coalesced
      float* obase = out + (size_t)bb * (COUT * HW) + hwbase + px;
#pragma unroll
      for (int pt = 0; pt < 2; ++pt)
#pragma unroll
        for (int r = 0; r < 16; ++r) {
          int j = wv * 32 + (r & 3) + 8 * (r >> 2) + 4 * hi;
          obase[j * HW + pt * 32] = hreg[pt][r] * inv[pt];
        }
    }
    __syncthreads();   // (c) hA ready / yF & red reusable
  }
}

extern "C" void kernel_launch(void* const* d_in, const int* in_sizes, int n_in,
                              void* d_out, int out_size, void* d_ws, size_t ws_size,
                              hipStream_t stream) {
  const float* x = (const float*)d_in[0];   // [32,256,32,32]
  const float* w = (const float*)d_in[1];   // [512,256]
  unsigned short* w1 = (unsigned short*)d_ws;          // 256 KB
  unsigned short* w2 = w1 + COUT * CIN;                // 256 KB
  float* out = (float*)d_out;

  prep_weights<<<dim3(512), dim3(256), 0, stream>>>(w, w1, w2);
  nnmf_kernel<<<dim3(512), dim3(1024), 0, stream>>>(x, w1, w2, out);
}